// Round 1
// baseline (1066.158 us; speedup 1.0000x reference)
//
#include <hip/hip_runtime.h>
#include <hip/hip_bf16.h>

#define N_NODES 50000
#define N_EDGES 1600000
#define ET (N_EDGES + N_NODES)
#define F_IN 1433
#define KP 1440              // F_IN padded to multiple of 32
#define HC 128               // HEADS*HID
#define NCLS 7
#define NEG 0.2f

typedef __attribute__((ext_vector_type(8))) short short8;
typedef __attribute__((ext_vector_type(4))) float f32x4;

__device__ __forceinline__ unsigned short f2bf(float f) {
    unsigned int u = __float_as_uint(f);
    u += 0x7FFFu + ((u >> 16) & 1u);   // round-to-nearest-even
    return (unsigned short)(u >> 16);
}

// ---------------- CSR build ----------------
__global__ void k_count(const int* __restrict__ ei, int* __restrict__ deg) {
    int t = blockIdx.x * 256 + threadIdx.x;
    if (t >= ET) return;
    int d = (t < N_EDGES) ? ei[N_EDGES + t] : (t - N_EDGES);
    atomicAdd(&deg[d], 1);
}

__global__ __launch_bounds__(256) void k_scan(const int* __restrict__ deg, int* __restrict__ offs) {
    __shared__ int sums[256];
    const int C = (N_NODES + 255) / 256;   // 196
    int t = threadIdx.x;
    int lo = t * C, hi = lo + C; if (hi > N_NODES) hi = N_NODES; if (lo > N_NODES) lo = N_NODES;
    int s = 0;
    for (int i = lo; i < hi; ++i) s += deg[i];
    sums[t] = s;
    __syncthreads();
    for (int st = 1; st < 256; st <<= 1) {
        int v = 0;
        if (t >= st) v = sums[t - st];
        __syncthreads();
        sums[t] += v;
        __syncthreads();
    }
    int run = (t == 0) ? 0 : sums[t - 1];
    for (int i = lo; i < hi; ++i) { offs[i] = run; run += deg[i]; }
    if (t == 255) offs[N_NODES] = run;
}

__global__ void k_scatter(const int* __restrict__ ei, const int* __restrict__ offs,
                          int* __restrict__ cur, int* __restrict__ csr) {
    int t = blockIdx.x * 256 + threadIdx.x;
    if (t >= ET) return;
    int s, d;
    if (t < N_EDGES) { s = ei[t]; d = ei[N_EDGES + t]; } else { s = d = t - N_EDGES; }
    int pos = offs[d] + atomicAdd(&cur[d], 1);
    csr[pos] = s;
}

// ---------------- W1 transpose + bf16 cast: Wt[n][k], k padded to KP ----------------
__global__ void k_wt(const float* __restrict__ W1, unsigned short* __restrict__ Wt) {
    int t = blockIdx.x * 256 + threadIdx.x;
    if (t >= HC * KP) return;
    int n = t / KP, k = t - n * KP;
    float v = (k < F_IN) ? W1[(size_t)k * HC + n] : 0.f;
    Wt[(size_t)n * KP + k] = f2bf(v);
}

// ---------------- Layer-1 GEMM: H[N][128] = X[N][1433] @ W1, bf16 MFMA ----------------
__global__ __launch_bounds__(256) void k_gemm1(const float* __restrict__ X,
                                               const unsigned short* __restrict__ Wt,
                                               float* __restrict__ H) {
    __shared__ unsigned short lA[64 * 40];    // 64 rows x 32 k, stride 40 (bank-spread)
    __shared__ unsigned short lB[128 * 40];   // 128 n   x 32 k, stride 40
    const int tid = threadIdx.x;
    const int wave = tid >> 6, lane = tid & 63;
    const int l15 = lane & 15, quad = lane >> 4;
    const int rowBase = blockIdx.x * 64;
    f32x4 acc[8];
#pragma unroll
    for (int i = 0; i < 8; ++i) acc[i] = (f32x4){0.f, 0.f, 0.f, 0.f};

    for (int k0 = 0; k0 < F_IN; k0 += 32) {
        // stage A tile (fp32 global -> bf16 LDS); 2048 elems, 8 per thread
#pragma unroll
        for (int it = 0; it < 2; ++it) {
            int flat4 = it * 256 + tid;            // 0..511 groups of 4
            int r = flat4 >> 3, c4 = (flat4 & 7) * 4;
            int row = rowBase + r;
            float v0 = 0.f, v1 = 0.f, v2 = 0.f, v3 = 0.f;
            if (row < N_NODES) {
                const float* p = X + (size_t)row * F_IN + (k0 + c4);
                int rem = F_IN - (k0 + c4);
                if (rem >= 4)      { v0 = p[0]; v1 = p[1]; v2 = p[2]; v3 = p[3]; }
                else {
                    if (rem > 0) v0 = p[0];
                    if (rem > 1) v1 = p[1];
                    if (rem > 2) v2 = p[2];
                }
            }
            unsigned short* q = &lA[r * 40 + c4];
            q[0] = f2bf(v0); q[1] = f2bf(v1); q[2] = f2bf(v2); q[3] = f2bf(v3);
        }
        // stage B tile (already bf16, padded -> no guards), 16B per thread x2
#pragma unroll
        for (int it = 0; it < 2; ++it) {
            int flat = it * 256 + tid;             // 0..511
            int n = flat >> 2, kb = (flat & 3) * 8;
            uint4 v = *reinterpret_cast<const uint4*>(Wt + (size_t)n * KP + k0 + kb);
            *reinterpret_cast<uint4*>(&lB[n * 40 + kb]) = v;
        }
        __syncthreads();
        short8 a = *reinterpret_cast<const short8*>(&lA[(wave * 16 + l15) * 40 + quad * 8]);
#pragma unroll
        for (int nt = 0; nt < 8; ++nt) {
            short8 b = *reinterpret_cast<const short8*>(&lB[(nt * 16 + l15) * 40 + quad * 8]);
            acc[nt] = __builtin_amdgcn_mfma_f32_16x16x32_bf16(a, b, acc[nt], 0, 0, 0);
        }
        __syncthreads();
    }
    const int rowW = rowBase + wave * 16 + quad * 4;
#pragma unroll
    for (int nt = 0; nt < 8; ++nt) {
#pragma unroll
        for (int r = 0; r < 4; ++r) {
            int row = rowW + r;
            if (row < N_NODES) H[(size_t)row * HC + nt * 16 + l15] = acc[nt][r];
        }
    }
}

// ---------------- attention scores layer 1: a_s/a_d [N][8] ----------------
__global__ void k_scores1(const float* __restrict__ H, const float* __restrict__ atS,
                          const float* __restrict__ atD, float* __restrict__ aS,
                          float* __restrict__ aD) {
    int i = blockIdx.x * 256 + threadIdx.x;
    if (i >= N_NODES * 8) return;
    int h = i & 7;
    const float4* hp = reinterpret_cast<const float4*>(H + (size_t)(i >> 3) * HC + h * 16);
    const float4* s4 = reinterpret_cast<const float4*>(atS + h * 16);
    const float4* d4 = reinterpret_cast<const float4*>(atD + h * 16);
    float s = 0.f, d = 0.f;
#pragma unroll
    for (int j = 0; j < 4; ++j) {
        float4 hv = hp[j], sv = s4[j], dv = d4[j];
        s += hv.x * sv.x + hv.y * sv.y + hv.z * sv.z + hv.w * sv.w;
        d += hv.x * dv.x + hv.y * dv.y + hv.z * dv.z + hv.w * dv.w;
    }
    aS[i] = s; aD[i] = d;
}

// ---------------- layer-1 aggregation (wave per node) + bias + ELU ----------------
__global__ __launch_bounds__(256) void k_agg1(const float* __restrict__ H,
        const float* __restrict__ aS, const float* __restrict__ aD,
        const int* __restrict__ offs, const int* __restrict__ deg,
        const int* __restrict__ csr, const float* __restrict__ b1,
        float* __restrict__ H1) {
    int wave = threadIdx.x >> 6, lane = threadIdx.x & 63;
    int n = blockIdx.x * 4 + wave;
    if (n >= N_NODES) return;
    int off = offs[n], dg = deg[n];
    int head = lane >> 3;                     // lane owns channels 2*lane, 2*lane+1
    float adv = aD[n * 8 + head];
    float z = 0.f;
    for (int i = 0; i < dg; ++i) {
        int s = csr[off + i];
        float e = aS[s * 8 + head] + adv;
        e = e > 0.f ? e : NEG * e;
        z += __expf(e);
    }
    float zinv = 1.f / z;
    float ax = 0.f, ay = 0.f;
    for (int i = 0; i < dg; ++i) {
        int s = csr[off + i];
        float e = aS[s * 8 + head] + adv;
        e = e > 0.f ? e : NEG * e;
        float alpha = __expf(e) * zinv;
        float2 hv = *reinterpret_cast<const float2*>(H + (size_t)s * HC + lane * 2);
        ax += alpha * hv.x; ay += alpha * hv.y;
    }
    int c = lane * 2;
    float v0 = ax + b1[c], v1 = ay + b1[c + 1];
    v0 = v0 > 0.f ? v0 : expm1f(v0);
    v1 = v1 > 0.f ? v1 : expm1f(v1);
    *reinterpret_cast<float2*>(H1 + (size_t)n * HC + c) = make_float2(v0, v1);
}

// ---------------- layer 2: H2 = H1 @ W2, scores (8 lanes per node) ----------------
__global__ void k_layer2(const float* __restrict__ H1, const float* __restrict__ W2,
                         const float* __restrict__ atS, const float* __restrict__ atD,
                         float* __restrict__ H2, float* __restrict__ aS2,
                         float* __restrict__ aD2) {
    int t = blockIdx.x * 256 + threadIdx.x;
    int n = t >> 3, sub = t & 7;
    if (n >= N_NODES) return;
    float acc[NCLS];
#pragma unroll
    for (int c = 0; c < NCLS; ++c) acc[c] = 0.f;
    const float* hp = H1 + (size_t)n * HC + sub * 16;
#pragma unroll
    for (int k = 0; k < 16; ++k) {
        float x = hp[k];
        const float* w = W2 + (size_t)(sub * 16 + k) * NCLS;
#pragma unroll
        for (int c = 0; c < NCLS; ++c) acc[c] += x * w[c];
    }
#pragma unroll
    for (int m = 1; m < 8; m <<= 1) {
#pragma unroll
        for (int c = 0; c < NCLS; ++c) acc[c] += __shfl_xor(acc[c], m, 64);
    }
    if (sub == 0) {
        float s = 0.f, d = 0.f;
#pragma unroll
        for (int c = 0; c < NCLS; ++c) {
            H2[(size_t)n * NCLS + c] = acc[c];
            s += acc[c] * atS[c];
            d += acc[c] * atD[c];
        }
        aS2[n] = s; aD2[n] = d;
    }
}

// ---------------- layer-2 aggregation (8 lanes per node) + bias -> out ----------------
__global__ void k_agg2(const float* __restrict__ H2, const float* __restrict__ aS2,
                       const float* __restrict__ aD2, const int* __restrict__ offs,
                       const int* __restrict__ deg, const int* __restrict__ csr,
                       const float* __restrict__ b2, float* __restrict__ out) {
    int t = blockIdx.x * 256 + threadIdx.x;
    int n = t >> 3, sub = t & 7;
    if (n >= N_NODES) return;
    int off = offs[n], dg = deg[n];
    float adv = aD2[n];
    float z = 0.f;
    for (int i = 0; i < dg; ++i) {
        int s = csr[off + i];
        float e = aS2[s] + adv;
        e = e > 0.f ? e : NEG * e;
        z += __expf(e);
    }
    float zinv = 1.f / z;
    float acc = 0.f;
    for (int i = 0; i < dg; ++i) {
        int s = csr[off + i];
        float e = aS2[s] + adv;
        e = e > 0.f ? e : NEG * e;
        float alpha = __expf(e) * zinv;
        if (sub < NCLS) acc += alpha * H2[(size_t)s * NCLS + sub];
    }
    if (sub < NCLS) out[(size_t)n * NCLS + sub] = acc + b2[sub];
}

extern "C" void kernel_launch(void* const* d_in, const int* in_sizes, int n_in,
                              void* d_out, int out_size, void* d_ws, size_t ws_size,
                              hipStream_t stream) {
    const float* X   = (const float*)d_in[0];
    const int*   EI  = (const int*)d_in[1];
    const float* W1  = (const float*)d_in[2];
    const float* at_s1 = (const float*)d_in[3];
    const float* at_d1 = (const float*)d_in[4];
    const float* b1  = (const float*)d_in[5];
    const float* W2  = (const float*)d_in[6];
    const float* at_s2 = (const float*)d_in[7];
    const float* at_d2 = (const float*)d_in[8];
    const float* b2  = (const float*)d_in[9];
    float* out = (float*)d_out;

    char* ws = (char*)d_ws;
    size_t o = 0;
    auto alloc = [&](size_t bytes) { size_t r = o; o += (bytes + 255) & ~(size_t)255; return r; };
    float* H    = (float*)(ws + alloc((size_t)N_NODES * HC * 4));
    float* H1   = (float*)(ws + alloc((size_t)N_NODES * HC * 4));
    float* aS1  = (float*)(ws + alloc((size_t)N_NODES * 8 * 4));
    float* aD1  = (float*)(ws + alloc((size_t)N_NODES * 8 * 4));
    float* H2   = (float*)(ws + alloc((size_t)N_NODES * NCLS * 4));
    float* aS2  = (float*)(ws + alloc((size_t)N_NODES * 4));
    float* aD2  = (float*)(ws + alloc((size_t)N_NODES * 4));
    int*   deg  = (int*)(ws + alloc((size_t)N_NODES * 4));
    int*   offs = (int*)(ws + alloc((size_t)(N_NODES + 1) * 4));
    int*   cur  = (int*)(ws + alloc((size_t)N_NODES * 4));
    int*   csr  = (int*)(ws + alloc((size_t)ET * 4));
    unsigned short* Wt = (unsigned short*)(ws + alloc((size_t)HC * KP * 2));

    hipMemsetAsync(deg, 0, (size_t)N_NODES * 4, stream);
    hipMemsetAsync(cur, 0, (size_t)N_NODES * 4, stream);

    k_count  <<<(ET + 255) / 256, 256, 0, stream>>>(EI, deg);
    k_scan   <<<1, 256, 0, stream>>>(deg, offs);
    k_scatter<<<(ET + 255) / 256, 256, 0, stream>>>(EI, offs, cur, csr);
    k_wt     <<<(HC * KP + 255) / 256, 256, 0, stream>>>(W1, Wt);
    k_gemm1  <<<(N_NODES + 63) / 64, 256, 0, stream>>>(X, Wt, H);
    k_scores1<<<(N_NODES * 8 + 255) / 256, 256, 0, stream>>>(H, at_s1, at_d1, aS1, aD1);
    k_agg1   <<<(N_NODES + 3) / 4, 256, 0, stream>>>(H, aS1, aD1, offs, deg, csr, b1, H1);
    k_layer2 <<<(N_NODES * 8 + 255) / 256, 256, 0, stream>>>(H1, W2, at_s2, at_d2, H2, aS2, aD2);
    k_agg2   <<<(N_NODES * 8 + 255) / 256, 256, 0, stream>>>(H2, aS2, aD2, offs, deg, csr, b2, out);
}

// Round 2
// 858.668 us; speedup vs baseline: 1.2416x; 1.2416x over previous
//
#include <hip/hip_runtime.h>
#include <hip/hip_bf16.h>

#define N_NODES 50000
#define N_EDGES 1600000
#define ET (N_EDGES + N_NODES)
#define F_IN 1433
#define KP 1440              // F_IN padded to multiple of 32
#define HC 128               // HEADS*HID
#define NCLS 7
#define NEG 0.2f

typedef __attribute__((ext_vector_type(8))) short short8;
typedef __attribute__((ext_vector_type(4))) float f32x4;

__device__ __forceinline__ unsigned short f2bf(float f) {
    unsigned int u = __float_as_uint(f);
    u += 0x7FFFu + ((u >> 16) & 1u);   // round-to-nearest-even
    return (unsigned short)(u >> 16);
}

// ---------------- CSR build ----------------
__global__ void k_count(const int* __restrict__ ei, int* __restrict__ deg) {
    int t = blockIdx.x * 256 + threadIdx.x;
    if (t >= ET) return;
    int d = (t < N_EDGES) ? ei[N_EDGES + t] : (t - N_EDGES);
    atomicAdd(&deg[d], 1);
}

__global__ __launch_bounds__(256) void k_scan(const int* __restrict__ deg, int* __restrict__ offs) {
    __shared__ int sums[256];
    const int C = (N_NODES + 255) / 256;   // 196
    int t = threadIdx.x;
    int lo = t * C, hi = lo + C; if (hi > N_NODES) hi = N_NODES; if (lo > N_NODES) lo = N_NODES;
    int s = 0;
    for (int i = lo; i < hi; ++i) s += deg[i];
    sums[t] = s;
    __syncthreads();
    for (int st = 1; st < 256; st <<= 1) {
        int v = 0;
        if (t >= st) v = sums[t - st];
        __syncthreads();
        sums[t] += v;
        __syncthreads();
    }
    int run = (t == 0) ? 0 : sums[t - 1];
    for (int i = lo; i < hi; ++i) { offs[i] = run; run += deg[i]; }
    if (t == 255) offs[N_NODES] = run;
}

__global__ void k_scatter(const int* __restrict__ ei, const int* __restrict__ offs,
                          int* __restrict__ cur, int* __restrict__ csr) {
    int t = blockIdx.x * 256 + threadIdx.x;
    if (t >= ET) return;
    int s, d;
    if (t < N_EDGES) { s = ei[t]; d = ei[N_EDGES + t]; } else { s = d = t - N_EDGES; }
    int pos = offs[d] + atomicAdd(&cur[d], 1);
    csr[pos] = s;
}

// ---------------- W1 transpose + bf16 cast: Wt[n][k], k padded to KP ----------------
__global__ void k_wt(const float* __restrict__ W1, unsigned short* __restrict__ Wt) {
    int t = blockIdx.x * 256 + threadIdx.x;
    if (t >= HC * KP) return;
    int n = t / KP, k = t - n * KP;
    float v = (k < F_IN) ? W1[(size_t)k * HC + n] : 0.f;
    Wt[(size_t)n * KP + k] = f2bf(v);
}

// ---------------- Layer-1 GEMM: H[N][128] = X[N][1433] @ W1, bf16 MFMA, 128x128 tile ----
__global__ __launch_bounds__(256) void k_gemm1(const float* __restrict__ X,
                                               const unsigned short* __restrict__ Wt,
                                               float* __restrict__ H) {
    __shared__ unsigned short lA[128 * 40];   // 128 rows x 32 k, stride 40 (2-way bank alias = free)
    __shared__ unsigned short lB[128 * 40];
    const int tid = threadIdx.x;
    const int wave = tid >> 6, lane = tid & 63;
    const int l15 = lane & 15, quad = lane >> 4;
    const int rowBase = blockIdx.x * 128;
    f32x4 acc[2][8];
#pragma unroll
    for (int m = 0; m < 2; ++m)
#pragma unroll
        for (int i = 0; i < 8; ++i) acc[m][i] = (f32x4){0.f, 0.f, 0.f, 0.f};

    for (int k0 = 0; k0 < KP; k0 += 32) {
        const bool tailK = (k0 + 32 > F_IN);
        // stage A tile: 128x32 fp32 -> bf16; 512 groups of 8, 2 per thread
#pragma unroll
        for (int g = 0; g < 2; ++g) {
            int flat = g * 256 + tid;
            int r = flat >> 2, k8 = (flat & 3) * 8;
            int row = rowBase + r;
            const float* p = X + (size_t)row * F_IN + k0 + k8;
            float v[8];
            if (row < N_NODES && !tailK) {
#pragma unroll
                for (int e = 0; e < 8; ++e) v[e] = p[e];
            } else {
#pragma unroll
                for (int e = 0; e < 8; ++e)
                    v[e] = (row < N_NODES && (k0 + k8 + e) < F_IN) ? p[e] : 0.f;
            }
            short8 sv;
#pragma unroll
            for (int e = 0; e < 8; ++e) sv[e] = (short)f2bf(v[e]);
            *reinterpret_cast<short8*>(&lA[r * 40 + k8]) = sv;
        }
        // stage B tile (bf16, padded -> guard-free), 16B per thread x2
#pragma unroll
        for (int g = 0; g < 2; ++g) {
            int flat = g * 256 + tid;
            int n = flat >> 2, kb = (flat & 3) * 8;
            uint4 v = *reinterpret_cast<const uint4*>(Wt + (size_t)n * KP + k0 + kb);
            *reinterpret_cast<uint4*>(&lB[n * 40 + kb]) = v;
        }
        __syncthreads();
        short8 a0 = *reinterpret_cast<const short8*>(&lA[(wave * 32 + l15) * 40 + quad * 8]);
        short8 a1 = *reinterpret_cast<const short8*>(&lA[(wave * 32 + 16 + l15) * 40 + quad * 8]);
#pragma unroll
        for (int nt = 0; nt < 8; ++nt) {
            short8 b = *reinterpret_cast<const short8*>(&lB[(nt * 16 + l15) * 40 + quad * 8]);
            acc[0][nt] = __builtin_amdgcn_mfma_f32_16x16x32_bf16(a0, b, acc[0][nt], 0, 0, 0);
            acc[1][nt] = __builtin_amdgcn_mfma_f32_16x16x32_bf16(a1, b, acc[1][nt], 0, 0, 0);
        }
        __syncthreads();
    }
#pragma unroll
    for (int m = 0; m < 2; ++m) {
        const int rowW = rowBase + wave * 32 + m * 16 + quad * 4;
#pragma unroll
        for (int nt = 0; nt < 8; ++nt) {
#pragma unroll
            for (int r = 0; r < 4; ++r) {
                int row = rowW + r;
                if (row < N_NODES) H[(size_t)row * HC + nt * 16 + l15] = acc[m][nt][r];
            }
        }
    }
}

// ---------------- attention scores layer 1: a_s/a_d [N][8] ----------------
__global__ void k_scores1(const float* __restrict__ H, const float* __restrict__ atS,
                          const float* __restrict__ atD, float* __restrict__ aS,
                          float* __restrict__ aD) {
    int i = blockIdx.x * 256 + threadIdx.x;
    if (i >= N_NODES * 8) return;
    int h = i & 7;
    const float4* hp = reinterpret_cast<const float4*>(H + (size_t)(i >> 3) * HC + h * 16);
    const float4* s4 = reinterpret_cast<const float4*>(atS + h * 16);
    const float4* d4 = reinterpret_cast<const float4*>(atD + h * 16);
    float s = 0.f, d = 0.f;
#pragma unroll
    for (int j = 0; j < 4; ++j) {
        float4 hv = hp[j], sv = s4[j], dv = d4[j];
        s += hv.x * sv.x + hv.y * sv.y + hv.z * sv.z + hv.w * sv.w;
        d += hv.x * dv.x + hv.y * dv.y + hv.z * dv.z + hv.w * dv.w;
    }
    aS[i] = s; aD[i] = d;
}

// ---------------- layer-1 aggregation: single-pass softmax, chunked csr + shfl ---------
__global__ __launch_bounds__(256) void k_agg1(const float* __restrict__ H,
        const float* __restrict__ aS, const float* __restrict__ aD,
        const int* __restrict__ offs, const int* __restrict__ deg,
        const int* __restrict__ csr, const float* __restrict__ b1,
        float* __restrict__ H1) {
    int wave = threadIdx.x >> 6, lane = threadIdx.x & 63;
    int n = blockIdx.x * 4 + wave;
    if (n >= N_NODES) return;
    int off = offs[n], dg = deg[n];
    int head = lane >> 3;                     // lane owns channels 2*lane, 2*lane+1
    float adv = aD[n * 8 + head];
    const float* Hc = H + lane * 2;
    float z = 0.f, ax = 0.f, ay = 0.f;
    for (int base = 0; base < dg; base += 64) {
        int cnt = dg - base; if (cnt > 64) cnt = 64;
        int myS = (lane < cnt) ? csr[off + base + lane] : 0;
        int j = 0;
        for (; j + 4 <= cnt; j += 4) {
            int s0 = __shfl(myS, j);
            int s1 = __shfl(myS, j + 1);
            int s2 = __shfl(myS, j + 2);
            int s3 = __shfl(myS, j + 3);
            float e0 = aS[s0 * 8 + head] + adv;
            float e1 = aS[s1 * 8 + head] + adv;
            float e2 = aS[s2 * 8 + head] + adv;
            float e3 = aS[s3 * 8 + head] + adv;
            float2 h0 = *reinterpret_cast<const float2*>(Hc + (size_t)s0 * HC);
            float2 h1 = *reinterpret_cast<const float2*>(Hc + (size_t)s1 * HC);
            float2 h2 = *reinterpret_cast<const float2*>(Hc + (size_t)s2 * HC);
            float2 h3 = *reinterpret_cast<const float2*>(Hc + (size_t)s3 * HC);
            e0 = e0 > 0.f ? e0 : NEG * e0;
            e1 = e1 > 0.f ? e1 : NEG * e1;
            e2 = e2 > 0.f ? e2 : NEG * e2;
            e3 = e3 > 0.f ? e3 : NEG * e3;
            float w0 = __expf(e0), w1 = __expf(e1), w2 = __expf(e2), w3 = __expf(e3);
            z += (w0 + w1) + (w2 + w3);
            ax += w0 * h0.x + w1 * h1.x + w2 * h2.x + w3 * h3.x;
            ay += w0 * h0.y + w1 * h1.y + w2 * h2.y + w3 * h3.y;
        }
        for (; j < cnt; ++j) {
            int s0 = __shfl(myS, j);
            float e0 = aS[s0 * 8 + head] + adv;
            float2 h0 = *reinterpret_cast<const float2*>(Hc + (size_t)s0 * HC);
            e0 = e0 > 0.f ? e0 : NEG * e0;
            float w0 = __expf(e0);
            z += w0; ax += w0 * h0.x; ay += w0 * h0.y;
        }
    }
    float zinv = 1.f / z;
    int c = lane * 2;
    float v0 = ax * zinv + b1[c], v1 = ay * zinv + b1[c + 1];
    v0 = v0 > 0.f ? v0 : expm1f(v0);
    v1 = v1 > 0.f ? v1 : expm1f(v1);
    *reinterpret_cast<float2*>(H1 + (size_t)n * HC + c) = make_float2(v0, v1);
}

// ---------------- layer 2: H2 = H1 @ W2, scores (8 lanes per node) ----------------
__global__ void k_layer2(const float* __restrict__ H1, const float* __restrict__ W2,
                         const float* __restrict__ atS, const float* __restrict__ atD,
                         float* __restrict__ H2, float* __restrict__ aS2,
                         float* __restrict__ aD2) {
    int t = blockIdx.x * 256 + threadIdx.x;
    int n = t >> 3, sub = t & 7;
    if (n >= N_NODES) return;
    float acc[NCLS];
#pragma unroll
    for (int c = 0; c < NCLS; ++c) acc[c] = 0.f;
    const float* hp = H1 + (size_t)n * HC + sub * 16;
#pragma unroll
    for (int k = 0; k < 16; ++k) {
        float x = hp[k];
        const float* w = W2 + (size_t)(sub * 16 + k) * NCLS;
#pragma unroll
        for (int c = 0; c < NCLS; ++c) acc[c] += x * w[c];
    }
#pragma unroll
    for (int m = 1; m < 8; m <<= 1) {
#pragma unroll
        for (int c = 0; c < NCLS; ++c) acc[c] += __shfl_xor(acc[c], m, 64);
    }
    if (sub == 0) {
        float s = 0.f, d = 0.f;
#pragma unroll
        for (int c = 0; c < NCLS; ++c) {
            H2[(size_t)n * NCLS + c] = acc[c];
            s += acc[c] * atS[c];
            d += acc[c] * atD[c];
        }
        aS2[n] = s; aD2[n] = d;
    }
}

// ---------------- layer-2 aggregation: single-pass softmax ----------------
__global__ void k_agg2(const float* __restrict__ H2, const float* __restrict__ aS2,
                       const float* __restrict__ aD2, const int* __restrict__ offs,
                       const int* __restrict__ deg, const int* __restrict__ csr,
                       const float* __restrict__ b2, float* __restrict__ out) {
    int t = blockIdx.x * 256 + threadIdx.x;
    int n = t >> 3, sub = t & 7;
    if (n >= N_NODES) return;
    int off = offs[n], dg = deg[n];
    int subc = sub < NCLS ? sub : NCLS - 1;   // lane 7 loads a dup, masked at the end
    float adv = aD2[n];
    float z = 0.f, acc = 0.f;
    int i = 0;
    for (; i + 2 <= dg; i += 2) {
        int s0 = csr[off + i], s1 = csr[off + i + 1];
        float e0 = aS2[s0] + adv, e1 = aS2[s1] + adv;
        float v0 = H2[(size_t)s0 * NCLS + subc];
        float v1 = H2[(size_t)s1 * NCLS + subc];
        e0 = e0 > 0.f ? e0 : NEG * e0;
        e1 = e1 > 0.f ? e1 : NEG * e1;
        float w0 = __expf(e0), w1 = __expf(e1);
        z += w0 + w1;
        acc += w0 * v0 + w1 * v1;
    }
    if (i < dg) {
        int s0 = csr[off + i];
        float e0 = aS2[s0] + adv;
        float v0 = H2[(size_t)s0 * NCLS + subc];
        e0 = e0 > 0.f ? e0 : NEG * e0;
        float w0 = __expf(e0);
        z += w0; acc += w0 * v0;
    }
    if (sub < NCLS) out[(size_t)n * NCLS + sub] = acc / z + b2[sub];
}

extern "C" void kernel_launch(void* const* d_in, const int* in_sizes, int n_in,
                              void* d_out, int out_size, void* d_ws, size_t ws_size,
                              hipStream_t stream) {
    const float* X   = (const float*)d_in[0];
    const int*   EI  = (const int*)d_in[1];
    const float* W1  = (const float*)d_in[2];
    const float* at_s1 = (const float*)d_in[3];
    const float* at_d1 = (const float*)d_in[4];
    const float* b1  = (const float*)d_in[5];
    const float* W2  = (const float*)d_in[6];
    const float* at_s2 = (const float*)d_in[7];
    const float* at_d2 = (const float*)d_in[8];
    const float* b2  = (const float*)d_in[9];
    float* out = (float*)d_out;

    char* ws = (char*)d_ws;
    size_t o = 0;
    auto alloc = [&](size_t bytes) { size_t r = o; o += (bytes + 255) & ~(size_t)255; return r; };
    float* H    = (float*)(ws + alloc((size_t)N_NODES * HC * 4));
    float* H1   = (float*)(ws + alloc((size_t)N_NODES * HC * 4));
    float* aS1  = (float*)(ws + alloc((size_t)N_NODES * 8 * 4));
    float* aD1  = (float*)(ws + alloc((size_t)N_NODES * 8 * 4));
    float* H2   = (float*)(ws + alloc((size_t)N_NODES * NCLS * 4));
    float* aS2  = (float*)(ws + alloc((size_t)N_NODES * 4));
    float* aD2  = (float*)(ws + alloc((size_t)N_NODES * 4));
    int*   deg  = (int*)(ws + alloc((size_t)N_NODES * 4));
    int*   offs = (int*)(ws + alloc((size_t)(N_NODES + 1) * 4));
    int*   cur  = (int*)(ws + alloc((size_t)N_NODES * 4));
    int*   csr  = (int*)(ws + alloc((size_t)ET * 4));
    unsigned short* Wt = (unsigned short*)(ws + alloc((size_t)HC * KP * 2));

    hipMemsetAsync(deg, 0, (size_t)N_NODES * 4, stream);
    hipMemsetAsync(cur, 0, (size_t)N_NODES * 4, stream);

    k_count  <<<(ET + 255) / 256, 256, 0, stream>>>(EI, deg);
    k_scan   <<<1, 256, 0, stream>>>(deg, offs);
    k_scatter<<<(ET + 255) / 256, 256, 0, stream>>>(EI, offs, cur, csr);
    k_wt     <<<(HC * KP + 255) / 256, 256, 0, stream>>>(W1, Wt);
    k_gemm1  <<<(N_NODES + 127) / 128, 256, 0, stream>>>(X, Wt, H);
    k_scores1<<<(N_NODES * 8 + 255) / 256, 256, 0, stream>>>(H, at_s1, at_d1, aS1, aD1);
    k_agg1   <<<(N_NODES + 3) / 4, 256, 0, stream>>>(H, aS1, aD1, offs, deg, csr, b1, H1);
    k_layer2 <<<(N_NODES * 8 + 255) / 256, 256, 0, stream>>>(H1, W2, at_s2, at_d2, H2, aS2, aD2);
    k_agg2   <<<(N_NODES * 8 + 255) / 256, 256, 0, stream>>>(H2, aS2, aD2, offs, deg, csr, b2, out);
}

// Round 3
// 840.992 us; speedup vs baseline: 1.2677x; 1.0210x over previous
//
#include <hip/hip_runtime.h>
#include <hip/hip_bf16.h>

#define N_NODES 50000
#define N_EDGES 1600000
#define ET (N_EDGES + N_NODES)
#define F_IN 1433
#define KP 1440              // F_IN padded to multiple of 32
#define NK (KP / 32)         // 45 K-steps
#define HC 128               // HEADS*HID
#define NCLS 7
#define NEG 0.2f

typedef __attribute__((ext_vector_type(8))) short short8;
typedef __attribute__((ext_vector_type(4))) float f32x4;

__device__ __forceinline__ unsigned short f2bf(float f) {
    unsigned int u = __float_as_uint(f);
    u += 0x7FFFu + ((u >> 16) & 1u);   // round-to-nearest-even
    return (unsigned short)(u >> 16);
}
__device__ __forceinline__ float bf2f(unsigned short u) {
    return __uint_as_float(((unsigned int)u) << 16);
}

// ---------------- CSR build ----------------
__global__ void k_count(const int* __restrict__ ei, int* __restrict__ deg) {
    int t = blockIdx.x * 256 + threadIdx.x;
    if (t >= ET) return;
    int d = (t < N_EDGES) ? ei[N_EDGES + t] : (t - N_EDGES);
    atomicAdd(&deg[d], 1);
}

__global__ __launch_bounds__(256) void k_scan(const int* __restrict__ deg, int* __restrict__ offs) {
    __shared__ int sums[256];
    const int C = (N_NODES + 255) / 256;   // 196
    int t = threadIdx.x;
    int lo = t * C, hi = lo + C; if (hi > N_NODES) hi = N_NODES; if (lo > N_NODES) lo = N_NODES;
    int s = 0;
    for (int i = lo; i < hi; ++i) s += deg[i];
    sums[t] = s;
    __syncthreads();
    for (int st = 1; st < 256; st <<= 1) {
        int v = 0;
        if (t >= st) v = sums[t - st];
        __syncthreads();
        sums[t] += v;
        __syncthreads();
    }
    int run = (t == 0) ? 0 : sums[t - 1];
    for (int i = lo; i < hi; ++i) { offs[i] = run; run += deg[i]; }
    if (t == 255) offs[N_NODES] = run;
}

__global__ void k_scatter(const int* __restrict__ ei, const int* __restrict__ offs,
                          int* __restrict__ cur, int* __restrict__ csr) {
    int t = blockIdx.x * 256 + threadIdx.x;
    if (t >= ET) return;
    int s, d;
    if (t < N_EDGES) { s = ei[t]; d = ei[N_EDGES + t]; } else { s = d = t - N_EDGES; }
    int pos = offs[d] + atomicAdd(&cur[d], 1);
    csr[pos] = s;
}

// ---------------- W1 transpose + bf16 cast: Wt[n][k], k padded to KP ----------------
__global__ void k_wt(const float* __restrict__ W1, unsigned short* __restrict__ Wt) {
    int t = blockIdx.x * 256 + threadIdx.x;
    if (t >= HC * KP) return;
    int n = t / KP, k = t - n * KP;
    float v = (k < F_IN) ? W1[(size_t)k * HC + n] : 0.f;
    Wt[(size_t)n * KP + k] = f2bf(v);
}

// ---- Layer-1 GEMM: Hb[N][128](bf16) = X[N][1433] @ W1, 128x128 tile, reg-pipelined ----
__global__ __launch_bounds__(256) void k_gemm1(const float* __restrict__ X,
                                               const unsigned short* __restrict__ Wt,
                                               unsigned short* __restrict__ Hb) {
    __shared__ unsigned short lA[128 * 32];   // stride 32 shorts = 64B row; 2 lanes/bank = free
    __shared__ unsigned short lB[128 * 32];
    const int tid = threadIdx.x;
    const int wave = tid >> 6, lane = tid & 63;
    const int l15 = lane & 15, quad = lane >> 4;
    const int rowBase = blockIdx.x * 128;

    // per-thread staging coords (2 groups of 8 elems each for A and B)
    const int rA0 = (tid) >> 2,        kA0 = (tid & 3) * 8;          // flat g=0
    const int rA1 = (256 + tid) >> 2,  kA1 = (tid & 3) * 8;          // flat g=1
    const bool rowOk0 = (rowBase + rA0) < N_NODES;
    const bool rowOk1 = (rowBase + rA1) < N_NODES;
    const float* pA0 = X + (size_t)(rowBase + rA0) * F_IN + kA0;
    const float* pA1 = X + (size_t)(rowBase + rA1) * F_IN + kA1;
    const unsigned short* pB0 = Wt + (size_t)(tid >> 2) * KP + kA0;
    const unsigned short* pB1 = Wt + (size_t)((256 + tid) >> 2) * KP + kA1;

    f32x4 acc[2][8];
#pragma unroll
    for (int m = 0; m < 2; ++m)
#pragma unroll
        for (int i = 0; i < 8; ++i) acc[m][i] = (f32x4){0.f, 0.f, 0.f, 0.f};

    float va[16];
    uint4 vb[2];

    auto prefetch = [&](int k0) {
        const bool tailK = (k0 + 32 > F_IN);
        if (!tailK) {
#pragma unroll
            for (int e = 0; e < 8; ++e) va[e]     = rowOk0 ? pA0[k0 + e] : 0.f;
#pragma unroll
            for (int e = 0; e < 8; ++e) va[8 + e] = rowOk1 ? pA1[k0 + e] : 0.f;
        } else {
#pragma unroll
            for (int e = 0; e < 8; ++e)
                va[e]     = (rowOk0 && (k0 + kA0 + e) < F_IN) ? pA0[k0 + e] : 0.f;
#pragma unroll
            for (int e = 0; e < 8; ++e)
                va[8 + e] = (rowOk1 && (k0 + kA1 + e) < F_IN) ? pA1[k0 + e] : 0.f;
        }
        vb[0] = *reinterpret_cast<const uint4*>(pB0 + k0);
        vb[1] = *reinterpret_cast<const uint4*>(pB1 + k0);
    };

    prefetch(0);
    for (int kt = 0; kt < NK; ++kt) {
        // regs -> LDS (convert A to bf16)
        short8 s0, s1;
#pragma unroll
        for (int e = 0; e < 8; ++e) { s0[e] = (short)f2bf(va[e]); s1[e] = (short)f2bf(va[8 + e]); }
        *reinterpret_cast<short8*>(&lA[(size_t)tid * 8])         = s0;
        *reinterpret_cast<short8*>(&lA[(size_t)(256 + tid) * 8]) = s1;
        *reinterpret_cast<uint4*>(&lB[(size_t)tid * 8])          = vb[0];
        *reinterpret_cast<uint4*>(&lB[(size_t)(256 + tid) * 8])  = vb[1];
        __syncthreads();
        if (kt + 1 < NK) prefetch((kt + 1) * 32);   // overlaps with ds_read + MFMA below
        short8 a0 = *reinterpret_cast<const short8*>(&lA[(wave * 32 + l15) * 32 + quad * 8]);
        short8 a1 = *reinterpret_cast<const short8*>(&lA[(wave * 32 + 16 + l15) * 32 + quad * 8]);
#pragma unroll
        for (int nt = 0; nt < 8; ++nt) {
            short8 b = *reinterpret_cast<const short8*>(&lB[(nt * 16 + l15) * 32 + quad * 8]);
            acc[0][nt] = __builtin_amdgcn_mfma_f32_16x16x32_bf16(a0, b, acc[0][nt], 0, 0, 0);
            acc[1][nt] = __builtin_amdgcn_mfma_f32_16x16x32_bf16(a1, b, acc[1][nt], 0, 0, 0);
        }
        __syncthreads();
    }
#pragma unroll
    for (int m = 0; m < 2; ++m) {
        const int rowW = rowBase + wave * 32 + m * 16 + quad * 4;
#pragma unroll
        for (int nt = 0; nt < 8; ++nt) {
#pragma unroll
            for (int r = 0; r < 4; ++r) {
                int row = rowW + r;
                if (row < N_NODES) Hb[(size_t)row * HC + nt * 16 + l15] = f2bf(acc[m][nt][r]);
            }
        }
    }
}

// ---------------- attention scores layer 1: a_s/a_d [N][8], bf16 H ----------------
__global__ void k_scores1(const unsigned short* __restrict__ Hb, const float* __restrict__ atS,
                          const float* __restrict__ atD, float* __restrict__ aS,
                          float* __restrict__ aD) {
    int i = blockIdx.x * 256 + threadIdx.x;
    if (i >= N_NODES * 8) return;
    int h = i & 7;
    const unsigned int* hp = reinterpret_cast<const unsigned int*>(Hb + (size_t)(i >> 3) * HC + h * 16);
    const float* sv = atS + h * 16;
    const float* dv = atD + h * 16;
    float s = 0.f, d = 0.f;
#pragma unroll
    for (int j = 0; j < 8; ++j) {
        unsigned int u = hp[j];
        float x = bf2f((unsigned short)(u & 0xFFFF));
        float y = bf2f((unsigned short)(u >> 16));
        s += x * sv[2 * j] + y * sv[2 * j + 1];
        d += x * dv[2 * j] + y * dv[2 * j + 1];
    }
    aS[i] = s; aD[i] = d;
}

// ------- layer-1 aggregation: single-pass softmax, chunked csr + shfl, unroll 8 -------
__global__ __launch_bounds__(256) void k_agg1(const unsigned short* __restrict__ Hb,
        const float* __restrict__ aS, const float* __restrict__ aD,
        const int* __restrict__ offs, const int* __restrict__ deg,
        const int* __restrict__ csr, const float* __restrict__ b1,
        float* __restrict__ H1) {
    int wave = threadIdx.x >> 6, lane = threadIdx.x & 63;
    int n = blockIdx.x * 4 + wave;
    if (n >= N_NODES) return;
    int off = offs[n], dg = deg[n];
    int head = lane >> 3;                     // lane owns channels 2*lane, 2*lane+1
    float adv = aD[n * 8 + head];
    const unsigned short* Hc = Hb + lane * 2;
    float z = 0.f, ax = 0.f, ay = 0.f;
    for (int base = 0; base < dg; base += 64) {
        int cnt = dg - base; if (cnt > 64) cnt = 64;
        int myS = (lane < cnt) ? csr[off + base + lane] : 0;
        int j = 0;
        for (; j + 8 <= cnt; j += 8) {
            int s[8];
#pragma unroll
            for (int q = 0; q < 8; ++q) s[q] = __shfl(myS, j + q);
            float e[8]; unsigned int hv[8];
#pragma unroll
            for (int q = 0; q < 8; ++q) {
                e[q] = aS[s[q] * 8 + head] + adv;
                hv[q] = *reinterpret_cast<const unsigned int*>(Hc + (size_t)s[q] * HC);
            }
#pragma unroll
            for (int q = 0; q < 8; ++q) {
                float eq = e[q];
                eq = eq > 0.f ? eq : NEG * eq;
                float w = __expf(eq);
                z += w;
                ax += w * bf2f((unsigned short)(hv[q] & 0xFFFF));
                ay += w * bf2f((unsigned short)(hv[q] >> 16));
            }
        }
        for (; j < cnt; ++j) {
            int s0 = __shfl(myS, j);
            float e0 = aS[s0 * 8 + head] + adv;
            unsigned int hv = *reinterpret_cast<const unsigned int*>(Hc + (size_t)s0 * HC);
            e0 = e0 > 0.f ? e0 : NEG * e0;
            float w0 = __expf(e0);
            z += w0;
            ax += w0 * bf2f((unsigned short)(hv & 0xFFFF));
            ay += w0 * bf2f((unsigned short)(hv >> 16));
        }
    }
    float zinv = 1.f / z;
    int c = lane * 2;
    float v0 = ax * zinv + b1[c], v1 = ay * zinv + b1[c + 1];
    v0 = v0 > 0.f ? v0 : expm1f(v0);
    v1 = v1 > 0.f ? v1 : expm1f(v1);
    *reinterpret_cast<float2*>(H1 + (size_t)n * HC + c) = make_float2(v0, v1);
}

// ---------------- layer 2: H2 = H1 @ W2, scores (8 lanes per node) ----------------
__global__ void k_layer2(const float* __restrict__ H1, const float* __restrict__ W2,
                         const float* __restrict__ atS, const float* __restrict__ atD,
                         float* __restrict__ H2, float* __restrict__ aS2,
                         float* __restrict__ aD2) {
    int t = blockIdx.x * 256 + threadIdx.x;
    int n = t >> 3, sub = t & 7;
    if (n >= N_NODES) return;
    float acc[NCLS];
#pragma unroll
    for (int c = 0; c < NCLS; ++c) acc[c] = 0.f;
    const float* hp = H1 + (size_t)n * HC + sub * 16;
#pragma unroll
    for (int k = 0; k < 16; ++k) {
        float x = hp[k];
        const float* w = W2 + (size_t)(sub * 16 + k) * NCLS;
#pragma unroll
        for (int c = 0; c < NCLS; ++c) acc[c] += x * w[c];
    }
#pragma unroll
    for (int m = 1; m < 8; m <<= 1) {
#pragma unroll
        for (int c = 0; c < NCLS; ++c) acc[c] += __shfl_xor(acc[c], m, 64);
    }
    if (sub == 0) {
        float s = 0.f, d = 0.f;
#pragma unroll
        for (int c = 0; c < NCLS; ++c) {
            H2[(size_t)n * NCLS + c] = acc[c];
            s += acc[c] * atS[c];
            d += acc[c] * atD[c];
        }
        aS2[n] = s; aD2[n] = d;
    }
}

// ---------------- layer-2 aggregation: single-pass softmax, unroll 4 ----------------
__global__ void k_agg2(const float* __restrict__ H2, const float* __restrict__ aS2,
                       const float* __restrict__ aD2, const int* __restrict__ offs,
                       const int* __restrict__ deg, const int* __restrict__ csr,
                       const float* __restrict__ b2, float* __restrict__ out) {
    int t = blockIdx.x * 256 + threadIdx.x;
    int n = t >> 3, sub = t & 7;
    if (n >= N_NODES) return;
    int off = offs[n], dg = deg[n];
    int subc = sub < NCLS ? sub : NCLS - 1;   // lane 7 loads a dup, masked at the end
    float adv = aD2[n];
    float z = 0.f, acc = 0.f;
    int i = 0;
    for (; i + 4 <= dg; i += 4) {
        int s0 = csr[off + i], s1 = csr[off + i + 1], s2 = csr[off + i + 2], s3 = csr[off + i + 3];
        float e0 = aS2[s0] + adv, e1 = aS2[s1] + adv, e2 = aS2[s2] + adv, e3 = aS2[s3] + adv;
        float v0 = H2[(size_t)s0 * NCLS + subc];
        float v1 = H2[(size_t)s1 * NCLS + subc];
        float v2 = H2[(size_t)s2 * NCLS + subc];
        float v3 = H2[(size_t)s3 * NCLS + subc];
        e0 = e0 > 0.f ? e0 : NEG * e0;
        e1 = e1 > 0.f ? e1 : NEG * e1;
        e2 = e2 > 0.f ? e2 : NEG * e2;
        e3 = e3 > 0.f ? e3 : NEG * e3;
        float w0 = __expf(e0), w1 = __expf(e1), w2 = __expf(e2), w3 = __expf(e3);
        z += (w0 + w1) + (w2 + w3);
        acc += w0 * v0 + w1 * v1 + w2 * v2 + w3 * v3;
    }
    for (; i < dg; ++i) {
        int s0 = csr[off + i];
        float e0 = aS2[s0] + adv;
        float v0 = H2[(size_t)s0 * NCLS + subc];
        e0 = e0 > 0.f ? e0 : NEG * e0;
        float w0 = __expf(e0);
        z += w0; acc += w0 * v0;
    }
    if (sub < NCLS) out[(size_t)n * NCLS + sub] = acc / z + b2[sub];
}

extern "C" void kernel_launch(void* const* d_in, const int* in_sizes, int n_in,
                              void* d_out, int out_size, void* d_ws, size_t ws_size,
                              hipStream_t stream) {
    const float* X   = (const float*)d_in[0];
    const int*   EI  = (const int*)d_in[1];
    const float* W1  = (const float*)d_in[2];
    const float* at_s1 = (const float*)d_in[3];
    const float* at_d1 = (const float*)d_in[4];
    const float* b1  = (const float*)d_in[5];
    const float* W2  = (const float*)d_in[6];
    const float* at_s2 = (const float*)d_in[7];
    const float* at_d2 = (const float*)d_in[8];
    const float* b2  = (const float*)d_in[9];
    float* out = (float*)d_out;

    char* ws = (char*)d_ws;
    size_t o = 0;
    auto alloc = [&](size_t bytes) { size_t r = o; o += (bytes + 255) & ~(size_t)255; return r; };
    unsigned short* Hb = (unsigned short*)(ws + alloc((size_t)N_NODES * HC * 2));
    float* H1   = (float*)(ws + alloc((size_t)N_NODES * HC * 4));
    float* aS1  = (float*)(ws + alloc((size_t)N_NODES * 8 * 4));
    float* aD1  = (float*)(ws + alloc((size_t)N_NODES * 8 * 4));
    float* H2   = (float*)(ws + alloc((size_t)N_NODES * NCLS * 4));
    float* aS2  = (float*)(ws + alloc((size_t)N_NODES * 4));
    float* aD2  = (float*)(ws + alloc((size_t)N_NODES * 4));
    int*   deg  = (int*)(ws + alloc((size_t)N_NODES * 4));
    int*   offs = (int*)(ws + alloc((size_t)(N_NODES + 1) * 4));
    int*   cur  = (int*)(ws + alloc((size_t)N_NODES * 4));
    int*   csr  = (int*)(ws + alloc((size_t)ET * 4));
    unsigned short* Wt = (unsigned short*)(ws + alloc((size_t)HC * KP * 2));

    hipMemsetAsync(deg, 0, (size_t)N_NODES * 4, stream);
    hipMemsetAsync(cur, 0, (size_t)N_NODES * 4, stream);

    k_count  <<<(ET + 255) / 256, 256, 0, stream>>>(EI, deg);
    k_scan   <<<1, 256, 0, stream>>>(deg, offs);
    k_scatter<<<(ET + 255) / 256, 256, 0, stream>>>(EI, offs, cur, csr);
    k_wt     <<<(HC * KP + 255) / 256, 256, 0, stream>>>(W1, Wt);
    k_gemm1  <<<(N_NODES + 127) / 128, 256, 0, stream>>>(X, Wt, Hb);
    k_scores1<<<(N_NODES * 8 + 255) / 256, 256, 0, stream>>>(Hb, at_s1, at_d1, aS1, aD1);
    k_agg1   <<<(N_NODES + 3) / 4, 256, 0, stream>>>(Hb, aS1, aD1, offs, deg, csr, b1, H1);
    k_layer2 <<<(N_NODES * 8 + 255) / 256, 256, 0, stream>>>(H1, W2, at_s2, at_d2, H2, aS2, aD2);
    k_agg2   <<<(N_NODES * 8 + 255) / 256, 256, 0, stream>>>(H2, aS2, aD2, offs, deg, csr, b2, out);
}